// Round 1
// baseline (5098.259 us; speedup 1.0000x reference)
//
#include <hip/hip_runtime.h>

// ---------------- problem constants ----------------
constexpr int Tn  = 256;     // timesteps
constexpr int INn = 10;      // input features
constexpr int Hn  = 20;      // hidden
constexpr int G4  = 80;      // 4*H
constexpr int Bn  = 8192;    // batch

constexpr int NB  = 64;      // cooperative grid blocks
constexpr int NT  = 1024;    // threads per block
constexpr int NW  = NT / 64; // waves per block
constexpr int BPB = Bn / NB; // batch rows per block = 128

constexpr int N_INST = 3 * Tn + 3 + 1;   // 3 reductions/step + 3 MLP (+pad)

// ---------------- ws layout (u32 units) ----------------
constexpr int WS_SLOTS = 0;                      // [N_INST][64] flag|maxbits
constexpr int WS_XMAX  = WS_SLOTS + N_INST * 64;
constexpr int WS_SX    = WS_XMAX + 64;           // f32 x-scale
constexpr int WS_WIH   = WS_SX + 64;             // 800  quantized w_ih
constexpr int WS_WHH   = WS_WIH + G4 * INn;      // 1600 quantized w_hh
constexpr int WS_W1    = WS_WHH + G4 * Hn;       // 1280
constexpr int WS_W2    = WS_W1 + 64 * Hn;        // 2048
constexpr int WS_W3    = WS_W2 + 32 * 64;        // 160
constexpr int WS_END   = WS_W3 + 5 * 32;         // ~217 KB total

constexpr float SIGS = (float)(1.0 / 63.0);
constexpr float TANS = (float)(1.0 / 31.0);

__device__ __forceinline__ float wave_max64(float v) {
#pragma unroll
  for (int off = 32; off; off >>= 1) v = fmaxf(v, __shfl_down(v, off, 64));
  return v;
}

// quant matching the reference op-for-op: clip then round(half-even) then *scale
__device__ __forceinline__ float quantq(float v, float s, float lo, float hi) {
  return __fmul_rn(rintf(fminf(fmaxf(v / s, lo), hi)), s);
}
__device__ __forceinline__ float sigm(float v) {
  return 1.0f / (1.0f + expf(-v));
}

// grid-wide max over one value per thread; one store + poll per block.
// slots[inst][64] must be pre-zeroed; flag = sign bit (values are |x| >= 0).
__device__ __forceinline__ float grid_max(float v, int inst, unsigned* wsu,
                                          float* s_red, float* s_bc) {
  const int tid = threadIdx.x;
  v = wave_max64(v);
  if ((tid & 63) == 0) s_red[tid >> 6] = v;
  __syncthreads();
  if (tid == 0) {
    float bm = s_red[0];
#pragma unroll
    for (int w = 1; w < NW; ++w) bm = fmaxf(bm, s_red[w]);
    unsigned bits = __float_as_uint(bm) | 0x80000000u;
    __hip_atomic_store(&wsu[WS_SLOTS + inst * 64 + blockIdx.x], bits,
                       __ATOMIC_RELEASE, __HIP_MEMORY_SCOPE_AGENT);
  }
  if (tid < NB) {  // wave 0 polls all 64 block slots (coalesced 256B)
    unsigned g;
    do {
      g = __hip_atomic_load(&wsu[WS_SLOTS + inst * 64 + tid],
                            __ATOMIC_ACQUIRE, __HIP_MEMORY_SCOPE_AGENT);
    } while (!(g & 0x80000000u));
    float gv = __uint_as_float(g & 0x7fffffffu);
    gv = wave_max64(gv);
    if (tid == 0) *s_bc = gv;
  }
  __syncthreads();
  return *s_bc;
}

// ---------------- setup kernels ----------------
__global__ void k_init(unsigned* wsu) {
  int idx = blockIdx.x * blockDim.x + threadIdx.x;
  for (int i = idx; i < WS_SX; i += gridDim.x * blockDim.x) wsu[i] = 0u;
}

__global__ void k_xmax(const float4* __restrict__ x4, unsigned* wsu) {
  float m = 0.f;
  int idx = blockIdx.x * blockDim.x + threadIdx.x;
  int stride = gridDim.x * blockDim.x;
  for (int i = idx; i < (Bn * Tn * INn) / 4; i += stride) {
    float4 v = x4[i];
    m = fmaxf(m, fmaxf(fmaxf(fabsf(v.x), fabsf(v.y)),
                       fmaxf(fabsf(v.z), fabsf(v.w))));
  }
  m = wave_max64(m);
  __shared__ float sred[4];
  if ((threadIdx.x & 63) == 0) sred[threadIdx.x >> 6] = m;
  __syncthreads();
  if (threadIdx.x == 0) {
    m = fmaxf(fmaxf(sred[0], sred[1]), fmaxf(sred[2], sred[3]));
    atomicMax(&wsu[WS_XMAX], __float_as_uint(m));  // non-neg f32: bit-monotone
  }
}

__device__ void quant_tensor(const float* __restrict__ src, int n, float* dst,
                             float* sred, float* sb) {
  const int tid = threadIdx.x;
  float m = 0.f;
  for (int i = tid; i < n; i += NT) m = fmaxf(m, fabsf(src[i]));
  m = wave_max64(m);
  __syncthreads();
  if ((tid & 63) == 0) sred[tid >> 6] = m;
  __syncthreads();
  if (tid == 0) {
    float bm = sred[0];
    for (int w = 1; w < NW; ++w) bm = fmaxf(bm, sred[w]);
    *sb = __fadd_rn(bm / 127.0f, 1e-8f);
  }
  __syncthreads();
  float s = *sb;
  for (int i = tid; i < n; i += NT) {
    float q = rintf(fminf(fmaxf(src[i] / s, -128.f), 127.f));
    dst[i] = __fmul_rn(q, s);
  }
}

__global__ __launch_bounds__(NT) void k_wq(const float* wih, const float* whh,
                                           const float* w1, const float* w2,
                                           const float* w3, unsigned* wsu) {
  float* wsf = (float*)wsu;
  __shared__ float sred[NW];
  __shared__ float sb;
  if (threadIdx.x == 0)
    wsf[WS_SX] = __fadd_rn(__uint_as_float(wsu[WS_XMAX]) / 127.0f, 1e-8f);
  quant_tensor(wih, G4 * INn, wsf + WS_WIH, sred, &sb);
  quant_tensor(whh, G4 * Hn,  wsf + WS_WHH, sred, &sb);
  quant_tensor(w1,  64 * Hn,  wsf + WS_W1,  sred, &sb);
  quant_tensor(w2,  32 * 64,  wsf + WS_W2,  sred, &sb);
  quant_tensor(w3,  5 * 32,   wsf + WS_W3,  sred, &sb);
}

// ---------------- main cooperative LSTM kernel ----------------
__global__ __launch_bounds__(NT, 1) void k_lstm(
    const float* __restrict__ x,
    const float* __restrict__ bih, const float* __restrict__ bhh,
    const float* __restrict__ b1, const float* __restrict__ b2,
    const float* __restrict__ b3,
    float* __restrict__ out, unsigned* __restrict__ wsu) {
  const float* wsf = (const float*)wsu;

  __shared__ float s_wih[G4][INn];
  __shared__ float s_whh[G4][Hn];
  __shared__ float s_bih[G4], s_bhh[G4];
  __shared__ float s_h[BPB][Hn];      // persistent hidden state
  __shared__ float s_c[BPB][Hn];      // persistent cell state
  __shared__ float s_pre[BPB][G4];    // pre-gates; later reused as l1[BPB][64]
  __shared__ float s_xs[BPB][INn];    // quantized x slice for step t
  __shared__ float s_l2[BPB][32];
  __shared__ float s_red[NW];
  __shared__ float s_bc;

  const int tid = threadIdx.x;
  const int b0 = blockIdx.x * BPB;

  for (int i = tid; i < G4 * INn; i += NT) (&s_wih[0][0])[i] = wsf[WS_WIH + i];
  for (int i = tid; i < G4 * Hn; i += NT) (&s_whh[0][0])[i] = wsf[WS_WHH + i];
  if (tid < G4) { s_bih[tid] = bih[tid]; s_bhh[tid] = bhh[tid]; }
  for (int i = tid; i < BPB * Hn; i += NT) {
    (&s_h[0][0])[i] = 0.f;
    (&s_c[0][0])[i] = 0.f;
  }
  const float sx = wsf[WS_SX];

  const int bl = tid >> 3;        // batch row (0..127) this thread's gates
  const int g0 = (tid & 7) * 10;  // first of 10 gate columns

  int inst = 0;
  __syncthreads();

  for (int t = 0; t < Tn; ++t) {
    // stage + quantize this step's x slice (also orders prev-step h writes)
    for (int e = tid; e < BPB * INn; e += NT) {
      int bi = e / INn, ii = e - bi * INn;
      float v = x[((b0 + bi) * Tn + t) * INn + ii];
      float q = rintf(fminf(fmaxf(v / sx, -128.f), 127.f));
      (&s_xs[0][0])[e] = __fmul_rn(q, sx);
    }
    __syncthreads();

    // pre-gates: xq@wih^T + b_ih + b_hh + h@whh^T
    float hreg[Hn], xreg[INn];
#pragma unroll
    for (int k = 0; k < Hn; k++) hreg[k] = s_h[bl][k];
#pragma unroll
    for (int i = 0; i < INn; i++) xreg[i] = s_xs[bl][i];
    float lm = 0.f;
#pragma unroll
    for (int gg = 0; gg < 10; ++gg) {
      int g = g0 + gg;
      float acc = 0.f;
#pragma unroll
      for (int i = 0; i < INn; i++) acc = fmaf(xreg[i], s_wih[g][i], acc);
      acc = __fadd_rn(acc, s_bih[g]);
      acc = __fadd_rn(acc, s_bhh[g]);
      float hd = 0.f;
#pragma unroll
      for (int k = 0; k < Hn; k++) hd = fmaf(hreg[k], s_whh[g][k], hd);
      float pre = __fadd_rn(acc, hd);
      s_pre[bl][g] = pre;
      lm = fmaxf(lm, fabsf(pre));
    }
    float s1 = __fadd_rn(grid_max(lm, inst++, wsu, s_red, &s_bc) / 31.0f, 1e-8f);

    // gate quant + nonlinearities + cell pre-activation
    float cpre[3], og[3], hpre[3];
    float lm2 = 0.f;
#pragma unroll
    for (int k = 0; k < 3; k++) {
      int e = tid + k * NT;
      if (e < BPB * Hn) {
        int cb = e / Hn, j = e - cb * Hn;
        float gi = quantq(s_pre[cb][j],      s1, -32.f, 31.f);
        float gf = quantq(s_pre[cb][20 + j], s1, -32.f, 31.f);
        float gg = quantq(s_pre[cb][40 + j], s1, -32.f, 31.f);
        float go = quantq(s_pre[cb][60 + j], s1, -32.f, 31.f);
        float iv = quantq(sigm(gi), SIGS, 0.f, 63.f);
        float fv = quantq(sigm(gf), SIGS, 0.f, 63.f);
        float gv = quantq(tanhf(gg), TANS, -32.f, 31.f);
        og[k]    = quantq(sigm(go), SIGS, 0.f, 63.f);
        float cp = __fadd_rn(__fmul_rn(fv, s_c[cb][j]), __fmul_rn(iv, gv));
        cpre[k] = cp;
        lm2 = fmaxf(lm2, fabsf(cp));
      }
    }
    float s2 = __fadd_rn(grid_max(lm2, inst++, wsu, s_red, &s_bc) / 31.0f, 1e-8f);

    float lm3 = 0.f;
#pragma unroll
    for (int k = 0; k < 3; k++) {
      int e = tid + k * NT;
      if (e < BPB * Hn) {
        int cb = e / Hn, j = e - cb * Hn;
        float cn = quantq(cpre[k], s2, -32.f, 31.f);
        s_c[cb][j] = cn;
        float tq = quantq(tanhf(cn), TANS, -32.f, 31.f);
        float hp = __fmul_rn(og[k], tq);
        hpre[k] = hp;
        lm3 = fmaxf(lm3, fabsf(hp));
      }
    }
    float s3 = __fadd_rn(grid_max(lm3, inst++, wsu, s_red, &s_bc) / 127.0f, 1e-8f);

#pragma unroll
    for (int k = 0; k < 3; k++) {
      int e = tid + k * NT;
      if (e < BPB * Hn) {
        int cb = e / Hn, j = e - cb * Hn;
        s_h[cb][j] = quantq(hpre[k], s3, -128.f, 127.f);
      }
    }
    // next iteration's staging __syncthreads orders s_h writes before reads
  }
  __syncthreads();

  // ---------------- MLP head ----------------
  // out0 = qrelu(hT, 6), in place in s_h
  {
    float r[3];
    float lm = 0.f;
#pragma unroll
    for (int k = 0; k < 3; k++) {
      int e = tid + k * NT;
      if (e < BPB * Hn) {
        r[k] = fmaxf((&s_h[0][0])[e], 0.f);
        lm = fmaxf(lm, r[k]);
      }
    }
    float s = __fadd_rn(grid_max(lm, inst++, wsu, s_red, &s_bc) / 63.0f, 1e-8f);
#pragma unroll
    for (int k = 0; k < 3; k++) {
      int e = tid + k * NT;
      if (e < BPB * Hn)
        (&s_h[0][0])[e] = __fmul_rn(rintf(fminf(fmaxf(r[k] / s, 0.f), 63.f)), s);
    }
  }
  __syncthreads();

  // l1 = qrelu(out0 @ w1^T + b1, 6)  -> s_l1 (aliases s_pre, 8192 <= 10240)
  float* s_l1 = &s_pre[0][0];
  {
    float a[8];
    float lm = 0.f;
#pragma unroll
    for (int k = 0; k < 8; k++) {
      int o = tid + k * NT;
      int cb = o >> 6, j = o & 63;
      float acc = 0.f;
#pragma unroll
      for (int kk = 0; kk < Hn; kk++)
        acc = fmaf(s_h[cb][kk], wsf[WS_W1 + j * Hn + kk], acc);
      acc = __fadd_rn(acc, b1[j]);
      acc = fmaxf(acc, 0.f);
      a[k] = acc;
      lm = fmaxf(lm, acc);
    }
    float s = __fadd_rn(grid_max(lm, inst++, wsu, s_red, &s_bc) / 63.0f, 1e-8f);
#pragma unroll
    for (int k = 0; k < 8; k++) {
      int o = tid + k * NT;
      s_l1[o] = __fmul_rn(rintf(fminf(fmaxf(a[k] / s, 0.f), 63.f)), s);
    }
  }
  __syncthreads();

  // l2 = qrelu(l1 @ w2^T + b2, 6) -> s_l2
  {
    float a[4];
    float lm = 0.f;
#pragma unroll
    for (int k = 0; k < 4; k++) {
      int o = tid + k * NT;
      int cb = o >> 5, j = o & 31;
      float acc = 0.f;
#pragma unroll
      for (int kk = 0; kk < 64; kk++)
        acc = fmaf(s_l1[cb * 64 + kk], wsf[WS_W2 + j * 64 + kk], acc);
      acc = __fadd_rn(acc, b2[j]);
      acc = fmaxf(acc, 0.f);
      a[k] = acc;
      lm = fmaxf(lm, acc);
    }
    float s = __fadd_rn(grid_max(lm, inst++, wsu, s_red, &s_bc) / 63.0f, 1e-8f);
#pragma unroll
    for (int k = 0; k < 4; k++) {
      int o = tid + k * NT;
      int cb = o >> 5, j = o & 31;
      s_l2[cb][j] = __fmul_rn(rintf(fminf(fmaxf(a[k] / s, 0.f), 63.f)), s);
    }
  }
  __syncthreads();

  // out = l2 @ w3^T + b3
  if (tid < BPB * 5) {
    int cb = tid / 5, j = tid - cb * 5;
    float acc = 0.f;
#pragma unroll
    for (int kk = 0; kk < 32; kk++)
      acc = fmaf(s_l2[cb][kk], wsf[WS_W3 + j * 32 + kk], acc);
    acc = __fadd_rn(acc, b3[j]);
    out[(b0 + cb) * 5 + j] = acc;
  }
}

extern "C" void kernel_launch(void* const* d_in, const int* in_sizes, int n_in,
                              void* d_out, int out_size, void* d_ws,
                              size_t ws_size, hipStream_t stream) {
  const float* x   = (const float*)d_in[0];
  const float* wih = (const float*)d_in[1];
  const float* whh = (const float*)d_in[2];
  const float* bih = (const float*)d_in[3];
  const float* bhh = (const float*)d_in[4];
  const float* w1  = (const float*)d_in[5];
  const float* b1  = (const float*)d_in[6];
  const float* w2  = (const float*)d_in[7];
  const float* b2  = (const float*)d_in[8];
  const float* w3  = (const float*)d_in[9];
  const float* b3  = (const float*)d_in[10];
  float* out = (float*)d_out;
  unsigned* wsu = (unsigned*)d_ws;

  k_init<<<dim3(256), dim3(256), 0, stream>>>(wsu);
  k_xmax<<<dim3(512), dim3(256), 0, stream>>>((const float4*)x, wsu);
  k_wq<<<dim3(1), dim3(NT), 0, stream>>>(wih, whh, w1, w2, w3, wsu);

  void* args[] = {(void*)&x,  (void*)&bih, (void*)&bhh, (void*)&b1,
                  (void*)&b2, (void*)&b3,  (void*)&out, (void*)&wsu};
  hipLaunchCooperativeKernel(k_lstm, dim3(NB), dim3(NT), args, 0, stream);
}